// Round 10
// baseline (158.444 us; speedup 1.0000x reference)
//
#include <hip/hip_runtime.h>
#include <math.h>

#define N_NODES 100000
#define N_EDGES 1000000
#define IN_DIM 64
#define OUT_DIM 64
#define CAP 32        // per-dst slots = 2 cache lines; Poisson(10), P(>32) ~ 3e-9
#define QCAP 131072   // per-partition queue capacity (125K avg + 18 sigma)
#define CNT_PITCH 12512
#define BINA_BLOCKS 120
#define BINA_CHUNK 8334
#define BINB_BLKS_PER_PART 128

typedef __attribute__((ext_vector_type(8)))  short bf16x8;
typedef __attribute__((ext_vector_type(16))) float f32x16;
typedef __attribute__((ext_vector_type(8)))  unsigned short u16x8;
typedef __attribute__((ext_vector_type(4)))  unsigned short u16x4;

__device__ __forceinline__ unsigned short f2bf(float f) {
    unsigned int u = __float_as_uint(f);
    u = (u + 0x7fffu + ((u >> 16) & 1u)) >> 16;   // RNE
    return (unsigned short)u;
}
__device__ __forceinline__ float bf2f(unsigned short h) {
    return __uint_as_float(((unsigned int)h) << 16);
}

// ---------------------------------------------------------------------------
// W prep: wt_hi/lo[n][k] = bf16 hi/lo split of W[k][n] (weight||root).
// k = rel*64+feat for k<256 (matches gather's agg layout), self-x at 256..319.
// ---------------------------------------------------------------------------
__global__ __launch_bounds__(320) void k_wprep(
    const float* __restrict__ weight, const float* __restrict__ root,
    unsigned short* __restrict__ wt_hi, unsigned short* __restrict__ wt_lo)
{
    int n = blockIdx.x;        // 0..63
    int k = threadIdx.x;       // 0..319
    float v = (k < 256) ? weight[k * 64 + n] : root[(k - 256) * 64 + n];
    unsigned short h = f2bf(v);
    wt_hi[n * 320 + k] = h;
    wt_lo[n * 320 + k] = f2bf(v - bf2f(h));
}

// ---------------------------------------------------------------------------
// x -> bf16 rows [N][64]; also zeroes cnt (partition-padded) and qcnt.
// ---------------------------------------------------------------------------
__global__ __launch_bounds__(256) void k_xprep(const float* __restrict__ x,
                                               unsigned short* __restrict__ xb,
                                               int* __restrict__ cnt,
                                               int* __restrict__ qcnt) {
    int u = blockIdx.x * 256 + threadIdx.x;        // 4-elem unit
    if (u < 8 * CNT_PITCH) cnt[u] = 0;
    if (u < 8) qcnt[u] = 0;
    if (u >= N_NODES * 16) return;
    float4 v = *(const float4*)(x + (size_t)u * 4);
    u16x4 h;
    h[0] = f2bf(v.x); h[1] = f2bf(v.y); h[2] = f2bf(v.z); h[3] = f2bf(v.w);
    *(u16x4*)(xb + (size_t)u * 4) = h;
}

// ---------------------------------------------------------------------------
// Bin pass A: partition edges into 8 queues by dst&7 (round-9 post-mortem:
// direct scatter's 62MB writeback = slot lines evicted by the 96MB edge
// stream before filling; fix = dense queue writes now, local scatter later).
// LDS histogram -> one global reserve-atomic per partition per block ->
// dense 8B-record writes into the reserved span.
// ---------------------------------------------------------------------------
__global__ __launch_bounds__(256) void k_binA(const int* __restrict__ ei,
                                              const int* __restrict__ et,
                                              int* __restrict__ qcnt,
                                              ulonglong2* /*unused*/,
                                              unsigned long long* __restrict__ queue) {
    __shared__ int hist[8], base[8], cur[8];
    int tid = threadIdx.x;
    int b0 = blockIdx.x * BINA_CHUNK;
    int b1 = b0 + BINA_CHUNK; if (b1 > N_EDGES) b1 = N_EDGES;
    if (tid < 8) { hist[tid] = 0; cur[tid] = 0; }
    __syncthreads();
    for (int e = b0 + tid; e < b1; e += 256)
        atomicAdd(&hist[ei[N_EDGES + e] & 7], 1);
    __syncthreads();
    if (tid < 8) base[tid] = atomicAdd(&qcnt[tid], hist[tid]);
    __syncthreads();
    for (int e = b0 + tid; e < b1; e += 256) {
        int d = ei[N_EDGES + e];
        int p = d & 7;
        int pos = base[p] + atomicAdd(&cur[p], 1);
        if (pos < QCAP) {
            unsigned long long rec =
                ((unsigned long long)(unsigned)d << 32) |
                (unsigned)((ei[e] << 2) | (et[e] & 3));
            queue[((size_t)p << 17) + pos] = rec;
        }
    }
}

// ---------------------------------------------------------------------------
// Bin pass B: partition p = blockIdx&7 (XCD-pinned) drains its queue into
// per-dst slot rows. Working set per XCD: 1.6MB slots + 50KB cnt + 1MB queue
// < 4MB L2 -> slot lines written back once. cnt partition-padded:
// cidx = (d&7)*CNT_PITCH + (d>>3) so counter lines never cross partitions.
// ---------------------------------------------------------------------------
__global__ __launch_bounds__(256) void k_binB(const int* __restrict__ qcnt,
                                              const unsigned long long* __restrict__ queue,
                                              int* __restrict__ cnt,
                                              int* __restrict__ slots) {
    int p = blockIdx.x & 7;
    int blk = blockIdx.x >> 3;
    int n = qcnt[p]; if (n > QCAP) n = QCAP;
    for (int i = blk * 256 + threadIdx.x; i < n; i += BINB_BLKS_PER_PART * 256) {
        unsigned long long rec = queue[((size_t)p << 17) + i];
        int d = (int)(rec >> 32);
        int sr = (int)(rec & 0xffffffffu);
        int pos = atomicAdd(&cnt[(d & 7) * CNT_PITCH + (d >> 3)], 1);
        if (pos < CAP) slots[(d << 5) + pos] = sr;
    }
}

// ---------------------------------------------------------------------------
// Gather (round-7 form, empirically best): one wave per node; lanes =
// 4 edge-slots x 16 feature-quarters; u16x4 loads, 4 parallel load chains;
// masked per-rel accumulation; xor16/32 reduce; lane (es,fq) outputs rel=es.
// ---------------------------------------------------------------------------
__global__ __launch_bounds__(256) void k_gather(
    const int* __restrict__ cnt, const int* __restrict__ slots,
    const unsigned short* __restrict__ xb, unsigned short* __restrict__ agg)
{
    int wv = threadIdx.x >> 6, ln = threadIdx.x & 63;
    int node = blockIdx.x * 4 + wv;
    int es = ln >> 4;          // edge slot 0..3
    int fq = ln & 15;          // feature quarter 0..15

    int deg = cnt[(node & 7) * CNT_PITCH + (node >> 3)];
    int m = (deg < CAP) ? deg : CAP;
    float inv = 1.0f / fmaxf((float)deg, 1.0f);

    float4 a0 = make_float4(0.f, 0.f, 0.f, 0.f);
    float4 a1 = a0, a2 = a0, a3 = a0;

    const int* srow = slots + (node << 5);
    for (int i = es; i < m; i += 4) {
        int p = srow[i];
        int r = p & 3;
        u16x4 vb = *(const u16x4*)(xb + ((size_t)(p >> 2) << 6) + (fq << 2));
        float vx = bf2f(vb[0]), vy = bf2f(vb[1]);
        float vz = bf2f(vb[2]), vw = bf2f(vb[3]);
        float m0 = (r == 0) ? 1.f : 0.f;
        float m1 = (r == 1) ? 1.f : 0.f;
        float m2 = (r == 2) ? 1.f : 0.f;
        float m3 = (r == 3) ? 1.f : 0.f;
        a0.x += vx * m0; a0.y += vy * m0; a0.z += vz * m0; a0.w += vw * m0;
        a1.x += vx * m1; a1.y += vy * m1; a1.z += vz * m1; a1.w += vw * m1;
        a2.x += vx * m2; a2.y += vy * m2; a2.z += vz * m2; a2.w += vw * m2;
        a3.x += vx * m3; a3.y += vy * m3; a3.z += vz * m3; a3.w += vw * m3;
    }

#define RED4(a)                                                   \
    a.x += __shfl_xor(a.x, 16); a.y += __shfl_xor(a.y, 16);       \
    a.z += __shfl_xor(a.z, 16); a.w += __shfl_xor(a.w, 16);       \
    a.x += __shfl_xor(a.x, 32); a.y += __shfl_xor(a.y, 32);       \
    a.z += __shfl_xor(a.z, 32); a.w += __shfl_xor(a.w, 32);
    RED4(a0) RED4(a1) RED4(a2) RED4(a3)
#undef RED4

    float4 w = a0;
    if (es == 1) w = a1;
    else if (es == 2) w = a2;
    else if (es == 3) w = a3;
    u16x4 h;
    h[0] = f2bf(w.x * inv); h[1] = f2bf(w.y * inv);
    h[2] = f2bf(w.z * inv); h[3] = f2bf(w.w * inv);
    *(u16x4*)(agg + (size_t)node * 256 + (ln << 2)) = h;   // k = es*64 + fq*4
}

// ---------------------------------------------------------------------------
// MFMA GEMM: tile 128 nodes x 64 outs, 4 waves; wave w = rows [w*32,w*32+32).
// A single bf16 (agg cols 0..255, xb cols 256..319), W hi/lo -> 2 MFMA passes.
// LDS rows 128B, byte ^= (row&7)<<4 swizzle on write & frag read.
// ---------------------------------------------------------------------------
__global__ __launch_bounds__(256) void k_gemm(
    const unsigned short* __restrict__ agg,
    const unsigned short* __restrict__ xb,
    const unsigned short* __restrict__ wt_hi,
    const unsigned short* __restrict__ wt_lo,
    const float* __restrict__ bias, float* __restrict__ out)
{
    __shared__ short As[128 * 64];   // [row][k] bf16, swizzled (16 KB)
    __shared__ short Bh[64 * 64];    // [n][k] bf16, swizzled  (8 KB)
    __shared__ short Bl[64 * 64];    //                        (8 KB)

    int tid = threadIdx.x;
    int n0 = blockIdx.x * 128;
    int lane = tid & 63, wv = tid >> 6;
    int lr = lane & 31, g = lane >> 5;

    f32x16 acc0 = {}, acc1 = {};

    for (int kc = 0; kc < 5; ++kc) {
        if (kc) __syncthreads();
        // stage A: 128 rows x 64 k = 16 KB
        #pragma unroll
        for (int i = 0; i < 4; ++i) {
            int u = i * 256 + tid;
            int row = u >> 3, i16 = u & 7;
            int node = n0 + row;
            if (node > N_NODES - 1) node = N_NODES - 1;   // clamp (epilogue guards)
            const unsigned short* src = (kc < 4)
                ? (agg + (size_t)node * 256 + kc * 64)
                : (xb + (size_t)node * 64);
            u16x8 v = *(const u16x8*)(src + i16 * 8);
            int off = row * 128 + ((i16 * 16) ^ ((row & 7) << 4));
            *(u16x8*)((char*)As + off) = v;
        }
        // stage B: 64 n x 64 k hi+lo
        #pragma unroll
        for (int i = 0; i < 2; ++i) {
            int u = i * 256 + tid;
            int n = u >> 3, i16 = u & 7;
            size_t s = (size_t)n * 320 + kc * 64 + i16 * 8;
            int off = n * 128 + ((i16 * 16) ^ ((n & 7) << 4));
            *(u16x8*)((char*)Bh + off) = *(const u16x8*)(wt_hi + s);
            *(u16x8*)((char*)Bl + off) = *(const u16x8*)(wt_lo + s);
        }
        __syncthreads();
        int ar = wv * 32 + lr;
        #pragma unroll
        for (int kst = 0; kst < 4; ++kst) {
            int kb = kst * 32 + g * 16;               // byte offset in 128B row
            int offA = ar * 128 + (kb ^ ((ar & 7) << 4));
            int offB = lr * 128 + (kb ^ ((lr & 7) << 4));
            bf16x8 ah  = *(const bf16x8*)((const char*)As + offA);
            bf16x8 bh0 = *(const bf16x8*)((const char*)Bh + offB);
            bf16x8 bl0 = *(const bf16x8*)((const char*)Bl + offB);
            bf16x8 bh1 = *(const bf16x8*)((const char*)Bh + offB + 32 * 128);
            bf16x8 bl1 = *(const bf16x8*)((const char*)Bl + offB + 32 * 128);
            acc0 = __builtin_amdgcn_mfma_f32_32x32x16_bf16(ah, bh0, acc0, 0, 0, 0);
            acc0 = __builtin_amdgcn_mfma_f32_32x32x16_bf16(ah, bl0, acc0, 0, 0, 0);
            acc1 = __builtin_amdgcn_mfma_f32_32x32x16_bf16(ah, bh1, acc1, 0, 0, 0);
            acc1 = __builtin_amdgcn_mfma_f32_32x32x16_bf16(ah, bl1, acc1, 0, 0, 0);
        }
    }

    // epilogue: C/D layout col=lane&31, row=(reg&3)+8*(reg>>2)+4*g (m74/m101)
    float b0 = bias[lr], b1 = bias[32 + lr];
    #pragma unroll
    for (int r = 0; r < 16; ++r) {
        int rowl = (r & 3) + ((r >> 2) << 3) + (g << 2);
        int node = n0 + wv * 32 + rowl;
        if (node < N_NODES) {
            out[(size_t)node * 64 + lr]      = tanhf(acc0[r] + b0);
            out[(size_t)node * 64 + 32 + lr] = tanhf(acc1[r] + b1);
        }
    }
}

extern "C" void kernel_launch(void* const* d_in, const int* in_sizes, int n_in,
                              void* d_out, int out_size, void* d_ws, size_t ws_size,
                              hipStream_t stream) {
    const float* x      = (const float*)d_in[0];
    const int*   ei     = (const int*)d_in[1];   // [2, E]
    const int*   et     = (const int*)d_in[2];   // [E]
    const float* weight = (const float*)d_in[3]; // [4,64,64]
    const float* root   = (const float*)d_in[4]; // [64,64]
    const float* bias   = (const float*)d_in[5]; // [64]
    float* out = (float*)d_out;

    // d_ws layout (~86 MB):
    unsigned short* agg   = (unsigned short*)d_ws;          // N*256 bf16 (51.2 MB)
    unsigned short* xb    = agg + (size_t)N_NODES * 256;    // N*64 bf16 (12.8 MB)
    unsigned short* wt_hi = xb + (size_t)N_NODES * 64;      // 64*320
    unsigned short* wt_lo = wt_hi + 64 * 320;               // 64*320
    int* cnt   = (int*)(wt_lo + 64 * 320);                  // 8*CNT_PITCH ints
    int* qcnt  = cnt + 8 * CNT_PITCH;                       // 8 ints
    int* slots = qcnt + 8;                                  // N*CAP ints (12.8 MB)
    unsigned long long* queue =
        (unsigned long long*)(slots + (size_t)N_NODES * CAP);  // 8*QCAP u64 (8.4 MB)

    k_wprep<<<64, 320, 0, stream>>>(weight, root, wt_hi, wt_lo);
    k_xprep<<<(N_NODES * 16 + 255) / 256, 256, 0, stream>>>(x, xb, cnt, qcnt);
    k_binA<<<BINA_BLOCKS, 256, 0, stream>>>(ei, et, qcnt, nullptr, queue);
    k_binB<<<8 * BINB_BLKS_PER_PART, 256, 0, stream>>>(qcnt, queue, cnt, slots);
    k_gather<<<N_NODES / 4, 256, 0, stream>>>(cnt, slots, xb, agg);
    k_gemm<<<(N_NODES + 127) / 128, 256, 0, stream>>>(agg, xb, wt_hi, wt_lo,
                                                      bias, out);
}

// Round 11
// 132.008 us; speedup vs baseline: 1.2003x; 1.2003x over previous
//
#include <hip/hip_runtime.h>
#include <hip/hip_fp16.h>
#include <math.h>

#define N_NODES 100000
#define N_EDGES 1000000
#define IN_DIM 64
#define OUT_DIM 64
#define CAP 32       // per-dst slots = 2 cache lines; Poisson(10), P(>32) ~ 3e-9
#define NPART 8      // dst partitions, pinned to XCDs via blockIdx & 7
#define PART_SZ 12500
#define SCAT_BLKS_PER_PART 128

typedef __attribute__((ext_vector_type(8)))  short bf16x8;
typedef __attribute__((ext_vector_type(16))) float f32x16;
typedef __attribute__((ext_vector_type(8)))  unsigned short u16x8;
typedef __attribute__((ext_vector_type(4)))  unsigned short u16x4;

__device__ __forceinline__ unsigned short f2bf(float f) {
    unsigned int u = __float_as_uint(f);
    u = (u + 0x7fffu + ((u >> 16) & 1u)) >> 16;   // RNE
    return (unsigned short)u;
}
__device__ __forceinline__ float bf2f(unsigned short h) {
    return __uint_as_float(((unsigned int)h) << 16);
}
__device__ __forceinline__ __half2 asH2(unsigned int u) {
    union { unsigned int u; __half2 h; } c; c.u = u; return c.h;
}
__device__ __forceinline__ unsigned int asU32(__half2 h) {
    union { unsigned int u; __half2 h; } c; c.h = h; return c.u;
}

// ---------------------------------------------------------------------------
// W prep: wt_hi/lo[n][k] = bf16 hi/lo split of W[k][n] (weight||root).
// ---------------------------------------------------------------------------
__global__ __launch_bounds__(320) void k_wprep(
    const float* __restrict__ weight, const float* __restrict__ root,
    unsigned short* __restrict__ wt_hi, unsigned short* __restrict__ wt_lo)
{
    int n = blockIdx.x;        // 0..63
    int k = threadIdx.x;       // 0..319
    float v = (k < 256) ? weight[k * 64 + n] : root[(k - 256) * 64 + n];
    unsigned short h = f2bf(v);
    wt_hi[n * 320 + k] = h;
    wt_lo[n * 320 + k] = f2bf(v - bf2f(h));
}

// ---------------------------------------------------------------------------
// x -> f16 rows (gather math) AND bf16 rows (GEMM self-x); zero cnt.
// ---------------------------------------------------------------------------
__global__ __launch_bounds__(256) void k_xprep(const float* __restrict__ x,
                                               unsigned short* __restrict__ xb,
                                               unsigned short* __restrict__ xh,
                                               int* __restrict__ cnt) {
    int u = blockIdx.x * 256 + threadIdx.x;        // 4-elem unit
    if (u < N_NODES) cnt[u] = 0;
    if (u >= N_NODES * 16) return;
    float4 v = *(const float4*)(x + (size_t)u * 4);
    u16x4 hb;
    hb[0] = f2bf(v.x); hb[1] = f2bf(v.y); hb[2] = f2bf(v.z); hb[3] = f2bf(v.w);
    *(u16x4*)(xb + (size_t)u * 4) = hb;
    uint2 st;
    st.x = asU32(__floats2half2_rn(v.x, v.y));
    st.y = asU32(__floats2half2_rn(v.z, v.w));
    *(uint2*)(xh + (size_t)u * 4) = st;
}

// ---------------------------------------------------------------------------
// XCD-sharded direct scatter (round-7 form, CAP=32): part=blockIdx&7 owns
// dst range [part*12500, +12500): slots (1.6MB) + cnt (50KB) stay in one
// XCD L2. Each part scans all edges (int4, L3-served).
// ---------------------------------------------------------------------------
__global__ __launch_bounds__(256) void k_scatter(const int* __restrict__ ei,
                                                 const int* __restrict__ et,
                                                 int* __restrict__ cnt,
                                                 int* __restrict__ slots) {
    int part = blockIdx.x & (NPART - 1);
    int blk  = blockIdx.x >> 3;
    int lo = part * PART_SZ, hi = lo + PART_SZ;

    const int4* dst4 = (const int4*)(ei + N_EDGES);
    const int4* src4 = (const int4*)ei;
    const int4* et4  = (const int4*)et;

    for (int u = blk * 256 + threadIdx.x; u < N_EDGES / 4;
         u += SCAT_BLKS_PER_PART * 256) {
        int4 d = dst4[u];
        int4 s = src4[u];
        int4 t = et4[u];
        #pragma unroll
        for (int j = 0; j < 4; ++j) {
            int dj = (j == 0) ? d.x : (j == 1) ? d.y : (j == 2) ? d.z : d.w;
            if (dj >= lo && dj < hi) {
                int sj = (j == 0) ? s.x : (j == 1) ? s.y : (j == 2) ? s.z : s.w;
                int tj = (j == 0) ? t.x : (j == 1) ? t.y : (j == 2) ? t.z : t.w;
                int pos = atomicAdd(&cnt[dj], 1);
                if (pos < CAP) slots[(dj << 5) + pos] = (sj << 2) | (tj & 3);
            }
        }
    }
}

// ---------------------------------------------------------------------------
// Gather: one wave per node; lanes = 4 edge-slots x 16 feature-quarters;
// f16 packed accumulation (v_pk_fma_f16 via __hfma2): per edge 2 dword
// loads + 4 masks + 8 hfma2 (was 4 cvt + 16 scalar FMA). half2 xor-reduce.
// Error: f16 accum noise / deg ~ 5e-4, under bf16-agg rounding (4e-3).
// ---------------------------------------------------------------------------
__global__ __launch_bounds__(256) void k_gather(
    const int* __restrict__ cnt, const int* __restrict__ slots,
    const unsigned short* __restrict__ xh, unsigned short* __restrict__ agg)
{
    int wv = threadIdx.x >> 6, ln = threadIdx.x & 63;
    int node = blockIdx.x * 4 + wv;
    int es = ln >> 4;          // edge slot 0..3 (also output rel)
    int fq = ln & 15;          // feature quarter 0..15

    int deg = cnt[node];
    int m = (deg < CAP) ? deg : CAP;
    float inv = 1.0f / fmaxf((float)deg, 1.0f);

    __half2 a0_01 = asH2(0), a0_23 = asH2(0);
    __half2 a1_01 = asH2(0), a1_23 = asH2(0);
    __half2 a2_01 = asH2(0), a2_23 = asH2(0);
    __half2 a3_01 = asH2(0), a3_23 = asH2(0);

    const int* srow = slots + (node << 5);
    for (int i = es; i < m; i += 4) {
        int p = srow[i];
        int r = p & 3;
        uint2 v = *(const uint2*)(xh + ((size_t)(p >> 2) << 6) + (fq << 2));
        __half2 h01 = asH2(v.x), h23 = asH2(v.y);
        __half2 m0 = asH2((r == 0) ? 0x3C003C00u : 0u);
        __half2 m1 = asH2((r == 1) ? 0x3C003C00u : 0u);
        __half2 m2 = asH2((r == 2) ? 0x3C003C00u : 0u);
        __half2 m3 = asH2((r == 3) ? 0x3C003C00u : 0u);
        a0_01 = __hfma2(h01, m0, a0_01); a0_23 = __hfma2(h23, m0, a0_23);
        a1_01 = __hfma2(h01, m1, a1_01); a1_23 = __hfma2(h23, m1, a1_23);
        a2_01 = __hfma2(h01, m2, a2_01); a2_23 = __hfma2(h23, m2, a2_23);
        a3_01 = __hfma2(h01, m3, a3_01); a3_23 = __hfma2(h23, m3, a3_23);
    }

#define REDH(a)                                                        \
    a = __hadd2(a, asH2(__shfl_xor(asU32(a), 16)));                    \
    a = __hadd2(a, asH2(__shfl_xor(asU32(a), 32)));
    REDH(a0_01) REDH(a0_23) REDH(a1_01) REDH(a1_23)
    REDH(a2_01) REDH(a2_23) REDH(a3_01) REDH(a3_23)
#undef REDH

    __half2 w01 = a0_01, w23 = a0_23;
    if (es == 1)      { w01 = a1_01; w23 = a1_23; }
    else if (es == 2) { w01 = a2_01; w23 = a2_23; }
    else if (es == 3) { w01 = a3_01; w23 = a3_23; }
    float2 f01 = __half22float2(w01);
    float2 f23 = __half22float2(w23);
    u16x4 h;
    h[0] = f2bf(f01.x * inv); h[1] = f2bf(f01.y * inv);
    h[2] = f2bf(f23.x * inv); h[3] = f2bf(f23.y * inv);
    *(u16x4*)(agg + (size_t)node * 256 + (ln << 2)) = h;   // k = es*64 + fq*4
}

// ---------------------------------------------------------------------------
// MFMA GEMM: tile 128 nodes x 64 outs, 4 waves; wave w = rows [w*32,w*32+32).
// A single bf16 (agg cols 0..255, xb cols 256..319), W hi/lo -> 2 MFMA passes.
// LDS rows 128B, byte ^= (row&7)<<4 swizzle on write & frag read.
// ---------------------------------------------------------------------------
__global__ __launch_bounds__(256) void k_gemm(
    const unsigned short* __restrict__ agg,
    const unsigned short* __restrict__ xb,
    const unsigned short* __restrict__ wt_hi,
    const unsigned short* __restrict__ wt_lo,
    const float* __restrict__ bias, float* __restrict__ out)
{
    __shared__ short As[128 * 64];   // [row][k] bf16, swizzled (16 KB)
    __shared__ short Bh[64 * 64];    // [n][k] bf16, swizzled  (8 KB)
    __shared__ short Bl[64 * 64];    //                        (8 KB)

    int tid = threadIdx.x;
    int n0 = blockIdx.x * 128;
    int lane = tid & 63, wv = tid >> 6;
    int lr = lane & 31, g = lane >> 5;

    f32x16 acc0 = {}, acc1 = {};

    for (int kc = 0; kc < 5; ++kc) {
        if (kc) __syncthreads();
        // stage A: 128 rows x 64 k = 16 KB
        #pragma unroll
        for (int i = 0; i < 4; ++i) {
            int u = i * 256 + tid;
            int row = u >> 3, i16 = u & 7;
            int node = n0 + row;
            if (node > N_NODES - 1) node = N_NODES - 1;   // clamp (epilogue guards)
            const unsigned short* src = (kc < 4)
                ? (agg + (size_t)node * 256 + kc * 64)
                : (xb + (size_t)node * 64);
            u16x8 v = *(const u16x8*)(src + i16 * 8);
            int off = row * 128 + ((i16 * 16) ^ ((row & 7) << 4));
            *(u16x8*)((char*)As + off) = v;
        }
        // stage B: 64 n x 64 k hi+lo
        #pragma unroll
        for (int i = 0; i < 2; ++i) {
            int u = i * 256 + tid;
            int n = u >> 3, i16 = u & 7;
            size_t s = (size_t)n * 320 + kc * 64 + i16 * 8;
            int off = n * 128 + ((i16 * 16) ^ ((n & 7) << 4));
            *(u16x8*)((char*)Bh + off) = *(const u16x8*)(wt_hi + s);
            *(u16x8*)((char*)Bl + off) = *(const u16x8*)(wt_lo + s);
        }
        __syncthreads();
        int ar = wv * 32 + lr;
        #pragma unroll
        for (int kst = 0; kst < 4; ++kst) {
            int kb = kst * 32 + g * 16;               // byte offset in 128B row
            int offA = ar * 128 + (kb ^ ((ar & 7) << 4));
            int offB = lr * 128 + (kb ^ ((lr & 7) << 4));
            bf16x8 ah  = *(const bf16x8*)((const char*)As + offA);
            bf16x8 bh0 = *(const bf16x8*)((const char*)Bh + offB);
            bf16x8 bl0 = *(const bf16x8*)((const char*)Bl + offB);
            bf16x8 bh1 = *(const bf16x8*)((const char*)Bh + offB + 32 * 128);
            bf16x8 bl1 = *(const bf16x8*)((const char*)Bl + offB + 32 * 128);
            acc0 = __builtin_amdgcn_mfma_f32_32x32x16_bf16(ah, bh0, acc0, 0, 0, 0);
            acc0 = __builtin_amdgcn_mfma_f32_32x32x16_bf16(ah, bl0, acc0, 0, 0, 0);
            acc1 = __builtin_amdgcn_mfma_f32_32x32x16_bf16(ah, bh1, acc1, 0, 0, 0);
            acc1 = __builtin_amdgcn_mfma_f32_32x32x16_bf16(ah, bl1, acc1, 0, 0, 0);
        }
    }

    // epilogue: C/D layout col=lane&31, row=(reg&3)+8*(reg>>2)+4*g (m74/m101)
    float b0 = bias[lr], b1 = bias[32 + lr];
    #pragma unroll
    for (int r = 0; r < 16; ++r) {
        int rowl = (r & 3) + ((r >> 2) << 3) + (g << 2);
        int node = n0 + wv * 32 + rowl;
        if (node < N_NODES) {
            out[(size_t)node * 64 + lr]      = tanhf(acc0[r] + b0);
            out[(size_t)node * 64 + 32 + lr] = tanhf(acc1[r] + b1);
        }
    }
}

extern "C" void kernel_launch(void* const* d_in, const int* in_sizes, int n_in,
                              void* d_out, int out_size, void* d_ws, size_t ws_size,
                              hipStream_t stream) {
    const float* x      = (const float*)d_in[0];
    const int*   ei     = (const int*)d_in[1];   // [2, E]
    const int*   et     = (const int*)d_in[2];   // [E]
    const float* weight = (const float*)d_in[3]; // [4,64,64]
    const float* root   = (const float*)d_in[4]; // [64,64]
    const float* bias   = (const float*)d_in[5]; // [64]
    float* out = (float*)d_out;

    // d_ws layout (~90 MB):
    unsigned short* agg   = (unsigned short*)d_ws;          // N*256 bf16 (51.2 MB)
    unsigned short* xb    = agg + (size_t)N_NODES * 256;    // N*64 bf16 (12.8 MB)
    unsigned short* xh    = xb + (size_t)N_NODES * 64;      // N*64 f16  (12.8 MB)
    unsigned short* wt_hi = xh + (size_t)N_NODES * 64;      // 64*320
    unsigned short* wt_lo = wt_hi + 64 * 320;               // 64*320
    int* cnt   = (int*)(wt_lo + 64 * 320);                  // N ints (0.4 MB)
    int* slots = cnt + N_NODES;                             // N*CAP ints (12.8 MB)

    k_wprep<<<64, 320, 0, stream>>>(weight, root, wt_hi, wt_lo);
    k_xprep<<<(N_NODES * 16 + 255) / 256, 256, 0, stream>>>(x, xb, xh, cnt);
    k_scatter<<<NPART * SCAT_BLKS_PER_PART, 256, 0, stream>>>(ei, et, cnt, slots);
    k_gather<<<N_NODES / 4, 256, 0, stream>>>(cnt, slots, xh, agg);
    k_gemm<<<(N_NODES + 127) / 128, 256, 0, stream>>>(agg, xb, wt_hi, wt_lo,
                                                      bias, out);
}